// Round 3
// baseline (364.389 us; speedup 1.0000x reference)
//
#include <hip/hip_runtime.h>
#include <float.h>

#define B_SZ   64
#define T_FR   20
#define K_SEL  5
#define C_CH   3
#define D_SKIM 245760
#define HW224  50176
#define F4_IMG 12544        // HW224/4
#define K1_BLOCKS 768
#define K1_TILES  5         // 768 * 5 * 64 == 245760
#define GP_PARTS  4
#define F4_PART   3136      // F4_IMG/4

// ---------------------------------------------------------------------------
// Kernel 1: per-block partial of fea = A[64,245760] @ W[245760,64].
// 768 blocks (3/CU) x 5 tiles of BK=64. LDS layout: At[d][b] (transposed,
// stride 68 -> all compute reads are 2-way bank aliased = free) and Ws[d][j]
// (stride 68). 4 waves split each tile's d-range (16 d each); each wave holds
// the full 64x64 partial as an 8x8 register tile: per d, 4 ds_read_b128
// feed 64 explicit FMAs (no register-array address casts -> no scratch).
// Epilogue: deterministic 4-round cross-wave LDS reduce, coalesced slab write.
// NOTE: kernel is idempotent (pure function of inputs -> slab), so it can be
// launched multiple times for timing amplification.
// ---------------------------------------------------------------------------
__global__ __launch_bounds__(256) void skim_gemm(
    const float* __restrict__ A, const float* __restrict__ W,
    float* __restrict__ partial) {
  __shared__ float At[64][68];   // At[d][b]
  __shared__ float Ws[64][68];   // Ws[d][j]
  const int t    = threadIdx.x;
  const int lane = t & 63;
  const int wav  = t >> 6;             // 0..3
  const int bo   = lane >> 3;          // 0..7
  const int b0   = bo << 3;
  const int j0   = (lane & 7) << 3;
  const int srow = t >> 4;             // 0..15 (staging)
  const int scol = (t & 15) << 2;      // 0..60 (staging)

  float acc[8][8];
#pragma unroll
  for (int i = 0; i < 8; ++i)
#pragma unroll
    for (int j = 0; j < 8; ++j) acc[i][j] = 0.f;

  for (int tile = 0; tile < K1_TILES; ++tile) {
    const long d0 = (long)(blockIdx.x * K1_TILES + tile) * 64;
    __syncthreads();                   // protect LDS from previous tile readers
#pragma unroll
    for (int p = 0; p < 4; ++p) {
      const int row = (p << 4) + srow; // 0..63
      float4 a4 = *reinterpret_cast<const float4*>(A + (long)row * D_SKIM + d0 + scol);
      At[scol + 0][row] = a4.x;        // At[d][b] = A[b][d0+d]
      At[scol + 1][row] = a4.y;
      At[scol + 2][row] = a4.z;
      At[scol + 3][row] = a4.w;
      float4 w4 = *reinterpret_cast<const float4*>(W + (d0 + row) * 64 + scol);
      *reinterpret_cast<float4*>(&Ws[row][scol]) = w4;
    }
    __syncthreads();
#pragma unroll
    for (int dd = 0; dd < 16; ++dd) {
      const int d = (wav << 4) + dd;
      const float4 alo = *reinterpret_cast<const float4*>(&At[d][b0]);
      const float4 ahi = *reinterpret_cast<const float4*>(&At[d][b0 + 4]);
      const float4 wlo = *reinterpret_cast<const float4*>(&Ws[d][j0]);
      const float4 whi = *reinterpret_cast<const float4*>(&Ws[d][j0 + 4]);
#define FMA_ROW(i, av)                                      \
      acc[i][0] = fmaf(av, wlo.x, acc[i][0]);               \
      acc[i][1] = fmaf(av, wlo.y, acc[i][1]);               \
      acc[i][2] = fmaf(av, wlo.z, acc[i][2]);               \
      acc[i][3] = fmaf(av, wlo.w, acc[i][3]);               \
      acc[i][4] = fmaf(av, whi.x, acc[i][4]);               \
      acc[i][5] = fmaf(av, whi.y, acc[i][5]);               \
      acc[i][6] = fmaf(av, whi.z, acc[i][6]);               \
      acc[i][7] = fmaf(av, whi.w, acc[i][7]);
      FMA_ROW(0, alo.x) FMA_ROW(1, alo.y) FMA_ROW(2, alo.z) FMA_ROW(3, alo.w)
      FMA_ROW(4, ahi.x) FMA_ROW(5, ahi.y) FMA_ROW(6, ahi.z) FMA_ROW(7, ahi.w)
#undef FMA_ROW
    }
  }
  // deterministic cross-wave reduce into the At area (4096 floats, stride 64)
  __syncthreads();
  float* red = &At[0][0];              // reuse, flat [64*64], logical stride 64
  for (int r = 0; r < 4; ++r) {
    if (wav == r) {
#pragma unroll
      for (int i = 0; i < 8; ++i)
#pragma unroll
        for (int jj = 0; jj < 8; ++jj) {
          const int c = (jj + bo) & 7;           // skew writes across banks
          const int addr = ((b0 + i) << 6) + j0 + c;
          if (r == 0) red[addr] = acc[i][c];
          else        red[addr] += acc[i][c];
        }
    }
    __syncthreads();
  }
  float* out = partial + (long)blockIdx.x * 4096;
#pragma unroll
  for (int k = 0; k < 16; ++k) out[(k << 8) + t] = red[(k << 8) + t];
}

// ---------------------------------------------------------------------------
// Kernel 2: reduce 768 partial slabs -> fea; relu(+b_skim); logits via W_pol;
// stable top-5 (strict >, lowest index on ties = jax.lax.top_k), sorted asc.
// ---------------------------------------------------------------------------
__global__ __launch_bounds__(256) void policy_topk(
    const float* __restrict__ partial, const float* __restrict__ b_skim,
    const float* __restrict__ W_pol, const float* __restrict__ b_pol,
    int* __restrict__ idx_out) {
  const int b    = blockIdx.x;
  const int t    = threadIdx.x;
  const int lane = t & 63;
  const int wav  = t >> 6;
  __shared__ float red[4][64];
  __shared__ float vsh[64];
  __shared__ float lgsh[20];

  const int P4 = K1_BLOCKS / 4;        // 192 slabs per wave
  const float* base = partial + (long)(wav * P4) * 4096 + b * 64 + lane;
  float s = 0.f;
#pragma unroll 16
  for (int p = 0; p < P4; ++p) s += base[(long)p * 4096];
  red[wav][lane] = s;
  __syncthreads();

  if (wav == 0) {
    float fea = ((red[0][lane] + red[1][lane]) + (red[2][lane] + red[3][lane]))
                + b_skim[lane];
    vsh[lane] = fmaxf(fea, 0.f);
  }
  __syncthreads();

  if (t < 20) {
    float lg = b_pol[t];
#pragma unroll 8
    for (int k = 0; k < 64; ++k) lg = fmaf(vsh[k], W_pol[k * 20 + t], lg);
    lgsh[t] = lg;
  }
  __syncthreads();

  if (t == 0) {
    float lg[20];
#pragma unroll
    for (int i = 0; i < 20; ++i) lg[i] = lgsh[i];
    int sel[K_SEL];
#pragma unroll
    for (int s5 = 0; s5 < K_SEL; ++s5) {
      int bi = 0; float bv = lg[0];
      for (int i = 1; i < 20; ++i)
        if (lg[i] > bv) { bv = lg[i]; bi = i; }
      sel[s5] = bi; lg[bi] = -FLT_MAX;
    }
#pragma unroll
    for (int a = 1; a < K_SEL; ++a) {
      int v = sel[a], c = a;
      while (c > 0 && sel[c - 1] > v) { sel[c] = sel[c - 1]; --c; }
      sel[c] = v;
    }
#pragma unroll
    for (int s5 = 0; s5 < K_SEL; ++s5) idx_out[b * K_SEL + s5] = sel[s5];
  }
}

// ---------------------------------------------------------------------------
// Kernel 3: partial spatial sums of the 5 selected frames.
// 4 parts per (b,s,c) image -> 3840 blocks == 15 blocks/CU (no tail).
// ---------------------------------------------------------------------------
__global__ __launch_bounds__(256) void gather_pool(
    const float* __restrict__ F224, const int* __restrict__ idx,
    float* __restrict__ pooled_part) {
  const int blk  = blockIdx.x;
  const int part = blk & 3;
  const int img  = blk >> 2;           // b*15 + s*3 + c
  const int b = img / 15;
  const int r = img % 15;
  const int s = r / 3;
  const int c = r % 3;
  const int fr = idx[b * K_SEL + s];
  const float4* p4 = reinterpret_cast<const float4*>(F224) +
      ((long)(b * T_FR + fr) * C_CH + c) * F4_IMG + part * F4_PART;
  float sum = 0.f;
#pragma unroll 4
  for (int i = threadIdx.x; i < F4_PART; i += 256) {
    float4 v = p4[i];
    sum += (v.x + v.y) + (v.z + v.w);
  }
#pragma unroll
  for (int off = 32; off; off >>= 1) sum += __shfl_down(sum, off);
  __shared__ float red[4];
  if ((threadIdx.x & 63) == 0) red[threadIdx.x >> 6] = sum;
  __syncthreads();
  if (threadIdx.x == 0) pooled_part[blk] = (red[0] + red[1]) + (red[2] + red[3]);
}

// ---------------------------------------------------------------------------
// Kernel 4: out[b][n] = b_eval[n] + sum_k pooled[b][k] * W_eval[k][n]
// ---------------------------------------------------------------------------
__global__ __launch_bounds__(512) void eval_gemm(
    const float* __restrict__ pooled_part, const float* __restrict__ W_eval,
    const float* __restrict__ b_eval, float* __restrict__ out) {
  const int b = blockIdx.x;
  const int t = threadIdx.x;
  __shared__ float sh[60];
  __shared__ float pk[15];
  if (t < 60) sh[t] = pooled_part[b * 60 + t];
  __syncthreads();
  if (t < 15)
    pk[t] = ((sh[t * 4] + sh[t * 4 + 1]) + (sh[t * 4 + 2] + sh[t * 4 + 3]))
            * (1.0f / HW224);
  __syncthreads();
  if (t < 400) {
    float o = b_eval[t];
#pragma unroll
    for (int k = 0; k < 15; ++k) o = fmaf(pk[k], W_eval[k * 400 + t], o);
    out[b * 400 + t] = o;
  }
}

// ---------------------------------------------------------------------------
extern "C" void kernel_launch(void* const* d_in, const int* in_sizes, int n_in,
                              void* d_out, int out_size, void* d_ws, size_t ws_size,
                              hipStream_t stream) {
  const float* F64    = (const float*)d_in[0];
  const float* F224   = (const float*)d_in[1];
  const float* W_skim = (const float*)d_in[2];
  const float* b_skim = (const float*)d_in[3];
  const float* W_pol  = (const float*)d_in[4];
  const float* b_pol  = (const float*)d_in[5];
  const float* W_eval = (const float*)d_in[6];
  const float* b_eval = (const float*)d_in[7];
  float* out = (float*)d_out;

  char* ws = (char*)d_ws;
  float* partial     = (float*)ws;                         // 768*4096 floats
  int*   idx         = (int*)(ws + (size_t)K1_BLOCKS * 4096 * 4);
  float* pooled_part = (float*)(ws + (size_t)K1_BLOCKS * 4096 * 4 + 1280);

  // DIAGNOSTIC AMPLIFICATION: skim launched 4x (idempotent slab writes).
  // dur_us = 4*skim + rest  ->  isolates skim per-launch cost this round.
  for (int rep = 0; rep < 4; ++rep)
    skim_gemm<<<K1_BLOCKS, 256, 0, stream>>>(F64, W_skim, partial);
  policy_topk<<<B_SZ, 256, 0, stream>>>(partial, b_skim, W_pol, b_pol, idx);
  gather_pool<<<B_SZ * K_SEL * C_CH * GP_PARTS, 256, 0, stream>>>(F224, idx, pooled_part);
  eval_gemm  <<<B_SZ, 512, 0, stream>>>(pooled_part, W_eval, b_eval, out);
}

// Round 4
// 85.111 us; speedup vs baseline: 4.2814x; 4.2814x over previous
//
#include <hip/hip_runtime.h>
#include <float.h>

#define B_SZ   64
#define T_FR   20
#define K_SEL  5
#define C_CH   3
#define D_SKIM 245760
#define HW224  50176
#define F4_IMG 12544        // HW224/4
#define K1_BLOCKS 768
#define K1_TILES  10        // 768 blocks * 10 tiles * BK32 == 245760
#define BK        32
#define GP_PARTS  4
#define F4_PART   3136      // F4_IMG/4

// compile-time float4 component pick (dp is an unrolled literal)
#define AC(v, dp) ((dp) == 0 ? (v).x : (dp) == 1 ? (v).y : (dp) == 2 ? (v).z : (v).w)

// ---------------------------------------------------------------------------
// Kernel 1: per-block partial of fea = A[64,245760] @ W[245760,64].
// 768 blocks x 10 tiles of BK=32, double-buffered global_load_lds (16B DMA,
// no VGPR round-trip, no ds_writes). A-tile [64][32] staged with PRE-SWIZZLED
// global source: LDS slot s holds global slot s ^ (row>>3), so compute's
// 8-row-strided b128 reads cover 8 distinct bank-quads (conflict-free).
// W-tile [32][64] linear (j0 stride-8 reads = 2-way alias = free).
// 4 waves split each tile's d-range (8 d each); 8x8 register tile per lane.
// 2-phase: issue tile t+1 DMA -> compute tile t -> vmcnt(0)+barrier.
// LDS 32KB -> 3 blocks/CU -> whole grid resident.
// ---------------------------------------------------------------------------
__global__ __launch_bounds__(256) void skim_gemm(
    const float* __restrict__ A, const float* __restrict__ W,
    float* __restrict__ partial) {
  __shared__ float lds[8192];          // [buf][As 2048 | Ws 2048] dwords
  const int t    = threadIdx.x;
  const int lane = t & 63;
  const int wav  = t >> 6;             // 0..3
  const int kb   = lane >> 3;          // 0..7 (b-group)
  const int b0   = kb << 3;
  const int j0   = (lane & 7) << 3;

  // staging geometry (per wave: 2 A-instrs + 2 W-instrs, 1KB DMA each)
  const int ga0 = 2 * wav;             // A-instr ids ga0, ga0+1
  const int arow0 = 8 * ga0 + (lane >> 3);          // block-local b row
  const int aslot0 = (lane & 7) ^ (ga0 & 7);        // pre-swizzled 16B slot
  const int arow1 = 8 * (ga0 + 1) + (lane >> 3);
  const int aslot1 = (lane & 7) ^ ((ga0 + 1) & 7);
  const int wrow0 = 4 * ga0 + (lane >> 4);          // tile-local d row
  const int wcol0 = (lane & 15) << 2;
  const int wrow1 = 4 * (ga0 + 1) + (lane >> 4);

  float acc[8][8];
#pragma unroll
  for (int i = 0; i < 8; ++i)
#pragma unroll
    for (int j = 0; j < 8; ++j) acc[i][j] = 0.f;

  const long dbase = (long)blockIdx.x * (K1_TILES * BK);

#define STAGE(bufsel, tile_)                                                   \
  {                                                                            \
    const long d0_ = dbase + (long)(tile_) * BK;                               \
    float* Ab = lds + (bufsel) * 4096;                                         \
    float* Wb = Ab + 2048;                                                     \
    __builtin_amdgcn_global_load_lds(                                          \
        (const __attribute__((address_space(1))) void*)(A + (long)arow0 * D_SKIM + d0_ + aslot0 * 4), \
        (__attribute__((address_space(3))) void*)(Ab + ga0 * 256), 16, 0, 0);  \
    __builtin_amdgcn_global_load_lds(                                          \
        (const __attribute__((address_space(1))) void*)(A + (long)arow1 * D_SKIM + d0_ + aslot1 * 4), \
        (__attribute__((address_space(3))) void*)(Ab + (ga0 + 1) * 256), 16, 0, 0); \
    __builtin_amdgcn_global_load_lds(                                          \
        (const __attribute__((address_space(1))) void*)(W + (d0_ + wrow0) * 64 + wcol0), \
        (__attribute__((address_space(3))) void*)(Wb + ga0 * 256), 16, 0, 0);  \
    __builtin_amdgcn_global_load_lds(                                          \
        (const __attribute__((address_space(1))) void*)(W + (d0_ + wrow1) * 64 + wcol0), \
        (__attribute__((address_space(3))) void*)(Wb + (ga0 + 1) * 256), 16, 0, 0); \
  }

  STAGE(0, 0)
  asm volatile("s_waitcnt vmcnt(0)" ::: "memory");
  __syncthreads();

  for (int tile = 0; tile < K1_TILES; ++tile) {
    if (tile + 1 < K1_TILES) STAGE((tile + 1) & 1, tile + 1)
    const float* Ab = lds + (tile & 1) * 4096;
    const float* Wb = Ab + 2048;
#pragma unroll
    for (int chunk = 0; chunk < 2; ++chunk) {
      const int dc = (wav << 3) + (chunk << 2);     // tile-local d base
      const int sw = dc ^ (kb << 2);                // swizzled dword col
      const float4 a0 = *reinterpret_cast<const float4*>(&Ab[(b0 + 0) * 32 + sw]);
      const float4 a1 = *reinterpret_cast<const float4*>(&Ab[(b0 + 1) * 32 + sw]);
      const float4 a2 = *reinterpret_cast<const float4*>(&Ab[(b0 + 2) * 32 + sw]);
      const float4 a3 = *reinterpret_cast<const float4*>(&Ab[(b0 + 3) * 32 + sw]);
      const float4 a4 = *reinterpret_cast<const float4*>(&Ab[(b0 + 4) * 32 + sw]);
      const float4 a5 = *reinterpret_cast<const float4*>(&Ab[(b0 + 5) * 32 + sw]);
      const float4 a6 = *reinterpret_cast<const float4*>(&Ab[(b0 + 6) * 32 + sw]);
      const float4 a7 = *reinterpret_cast<const float4*>(&Ab[(b0 + 7) * 32 + sw]);
#pragma unroll
      for (int dp = 0; dp < 4; ++dp) {
        const float4 wlo = *reinterpret_cast<const float4*>(&Wb[(dc + dp) * 64 + j0]);
        const float4 whi = *reinterpret_cast<const float4*>(&Wb[(dc + dp) * 64 + j0 + 4]);
#define FMA_ROW(i, av)                             \
        acc[i][0] = fmaf(av, wlo.x, acc[i][0]);    \
        acc[i][1] = fmaf(av, wlo.y, acc[i][1]);    \
        acc[i][2] = fmaf(av, wlo.z, acc[i][2]);    \
        acc[i][3] = fmaf(av, wlo.w, acc[i][3]);    \
        acc[i][4] = fmaf(av, whi.x, acc[i][4]);    \
        acc[i][5] = fmaf(av, whi.y, acc[i][5]);    \
        acc[i][6] = fmaf(av, whi.z, acc[i][6]);    \
        acc[i][7] = fmaf(av, whi.w, acc[i][7]);
        FMA_ROW(0, AC(a0, dp)) FMA_ROW(1, AC(a1, dp))
        FMA_ROW(2, AC(a2, dp)) FMA_ROW(3, AC(a3, dp))
        FMA_ROW(4, AC(a4, dp)) FMA_ROW(5, AC(a5, dp))
        FMA_ROW(6, AC(a6, dp)) FMA_ROW(7, AC(a7, dp))
#undef FMA_ROW
      }
    }
    asm volatile("s_waitcnt vmcnt(0)" ::: "memory");
    __syncthreads();
  }
#undef STAGE

  // ---- 2-round cross-wave reduce reusing the 32KB staging LDS ----
  // region0 = lds[0..4095], region1 = lds[4096..8191]
  float* reg = lds + ((wav & 1) ? 4096 : 0);
  if (wav < 2) {
#pragma unroll
    for (int i = 0; i < 8; ++i) {
      *reinterpret_cast<float4*>(&reg[(b0 + i) * 64 + j0])     =
          make_float4(acc[i][0], acc[i][1], acc[i][2], acc[i][3]);
      *reinterpret_cast<float4*>(&reg[(b0 + i) * 64 + j0 + 4]) =
          make_float4(acc[i][4], acc[i][5], acc[i][6], acc[i][7]);
    }
  }
  __syncthreads();
  if (wav >= 2) {
#pragma unroll
    for (int i = 0; i < 8; ++i) {
      float4 lo = *reinterpret_cast<const float4*>(&reg[(b0 + i) * 64 + j0]);
      float4 hi = *reinterpret_cast<const float4*>(&reg[(b0 + i) * 64 + j0 + 4]);
      lo.x += acc[i][0]; lo.y += acc[i][1]; lo.z += acc[i][2]; lo.w += acc[i][3];
      hi.x += acc[i][4]; hi.y += acc[i][5]; hi.z += acc[i][6]; hi.w += acc[i][7];
      *reinterpret_cast<float4*>(&reg[(b0 + i) * 64 + j0])     = lo;
      *reinterpret_cast<float4*>(&reg[(b0 + i) * 64 + j0 + 4]) = hi;
    }
  }
  __syncthreads();
  const float4* r0 = reinterpret_cast<const float4*>(lds);
  const float4* r1 = reinterpret_cast<const float4*>(lds + 4096);
  float4* out = reinterpret_cast<float4*>(partial + (long)blockIdx.x * 4096);
#pragma unroll
  for (int k = 0; k < 4; ++k) {
    const int e = t + k * 256;
    float4 v0 = r0[e], v1 = r1[e];
    out[e] = make_float4(v0.x + v1.x, v0.y + v1.y, v0.z + v1.z, v0.w + v1.w);
  }
}

// ---------------------------------------------------------------------------
// Kernel 2: reduce 768 partial slabs -> fea; relu(+b_skim); logits via W_pol;
// stable top-5 (strict >, lowest index on ties = jax.lax.top_k), sorted asc.
// ---------------------------------------------------------------------------
__global__ __launch_bounds__(256) void policy_topk(
    const float* __restrict__ partial, const float* __restrict__ b_skim,
    const float* __restrict__ W_pol, const float* __restrict__ b_pol,
    int* __restrict__ idx_out) {
  const int b    = blockIdx.x;
  const int t    = threadIdx.x;
  const int lane = t & 63;
  const int wav  = t >> 6;
  __shared__ float red[4][64];
  __shared__ float vsh[64];
  __shared__ float lgsh[20];

  const int P4 = K1_BLOCKS / 4;        // 192 slabs per wave
  const float* base = partial + (long)(wav * P4) * 4096 + b * 64 + lane;
  float s = 0.f;
#pragma unroll 16
  for (int p = 0; p < P4; ++p) s += base[(long)p * 4096];
  red[wav][lane] = s;
  __syncthreads();

  if (wav == 0) {
    float fea = ((red[0][lane] + red[1][lane]) + (red[2][lane] + red[3][lane]))
                + b_skim[lane];
    vsh[lane] = fmaxf(fea, 0.f);
  }
  __syncthreads();

  if (t < 20) {
    float lg = b_pol[t];
#pragma unroll 8
    for (int k = 0; k < 64; ++k) lg = fmaf(vsh[k], W_pol[k * 20 + t], lg);
    lgsh[t] = lg;
  }
  __syncthreads();

  if (t == 0) {
    float lg[20];
#pragma unroll
    for (int i = 0; i < 20; ++i) lg[i] = lgsh[i];
    int sel[K_SEL];
#pragma unroll
    for (int s5 = 0; s5 < K_SEL; ++s5) {
      int bi = 0; float bv = lg[0];
      for (int i = 1; i < 20; ++i)
        if (lg[i] > bv) { bv = lg[i]; bi = i; }
      sel[s5] = bi; lg[bi] = -FLT_MAX;
    }
#pragma unroll
    for (int a = 1; a < K_SEL; ++a) {
      int v = sel[a], c = a;
      while (c > 0 && sel[c - 1] > v) { sel[c] = sel[c - 1]; --c; }
      sel[c] = v;
    }
#pragma unroll
    for (int s5 = 0; s5 < K_SEL; ++s5) idx_out[b * K_SEL + s5] = sel[s5];
  }
}

// ---------------------------------------------------------------------------
// Kernel 3: partial spatial sums of the 5 selected frames.
// 4 parts per (b,s,c) image -> 3840 blocks == 15 blocks/CU (no tail).
// ---------------------------------------------------------------------------
__global__ __launch_bounds__(256) void gather_pool(
    const float* __restrict__ F224, const int* __restrict__ idx,
    float* __restrict__ pooled_part) {
  const int blk  = blockIdx.x;
  const int part = blk & 3;
  const int img  = blk >> 2;           // b*15 + s*3 + c
  const int b = img / 15;
  const int r = img % 15;
  const int s = r / 3;
  const int c = r % 3;
  const int fr = idx[b * K_SEL + s];
  const float4* p4 = reinterpret_cast<const float4*>(F224) +
      ((long)(b * T_FR + fr) * C_CH + c) * F4_IMG + part * F4_PART;
  float sum = 0.f;
#pragma unroll 4
  for (int i = threadIdx.x; i < F4_PART; i += 256) {
    float4 v = p4[i];
    sum += (v.x + v.y) + (v.z + v.w);
  }
#pragma unroll
  for (int off = 32; off; off >>= 1) sum += __shfl_down(sum, off);
  __shared__ float red[4];
  if ((threadIdx.x & 63) == 0) red[threadIdx.x >> 6] = sum;
  __syncthreads();
  if (threadIdx.x == 0) pooled_part[blk] = (red[0] + red[1]) + (red[2] + red[3]);
}

// ---------------------------------------------------------------------------
// Kernel 4: out[b][n] = b_eval[n] + sum_k pooled[b][k] * W_eval[k][n]
// ---------------------------------------------------------------------------
__global__ __launch_bounds__(512) void eval_gemm(
    const float* __restrict__ pooled_part, const float* __restrict__ W_eval,
    const float* __restrict__ b_eval, float* __restrict__ out) {
  const int b = blockIdx.x;
  const int t = threadIdx.x;
  __shared__ float sh[60];
  __shared__ float pk[15];
  if (t < 60) sh[t] = pooled_part[b * 60 + t];
  __syncthreads();
  if (t < 15)
    pk[t] = ((sh[t * 4] + sh[t * 4 + 1]) + (sh[t * 4 + 2] + sh[t * 4 + 3]))
            * (1.0f / HW224);
  __syncthreads();
  if (t < 400) {
    float o = b_eval[t];
#pragma unroll
    for (int k = 0; k < 15; ++k) o = fmaf(pk[k], W_eval[k * 400 + t], o);
    out[b * 400 + t] = o;
  }
}

// ---------------------------------------------------------------------------
extern "C" void kernel_launch(void* const* d_in, const int* in_sizes, int n_in,
                              void* d_out, int out_size, void* d_ws, size_t ws_size,
                              hipStream_t stream) {
  const float* F64    = (const float*)d_in[0];
  const float* F224   = (const float*)d_in[1];
  const float* W_skim = (const float*)d_in[2];
  const float* b_skim = (const float*)d_in[3];
  const float* W_pol  = (const float*)d_in[4];
  const float* b_pol  = (const float*)d_in[5];
  const float* W_eval = (const float*)d_in[6];
  const float* b_eval = (const float*)d_in[7];
  float* out = (float*)d_out;

  char* ws = (char*)d_ws;
  float* partial     = (float*)ws;                         // 768*4096 floats
  int*   idx         = (int*)(ws + (size_t)K1_BLOCKS * 4096 * 4);
  float* pooled_part = (float*)(ws + (size_t)K1_BLOCKS * 4096 * 4 + 1280);

  skim_gemm  <<<K1_BLOCKS, 256, 0, stream>>>(F64, W_skim, partial);
  policy_topk<<<B_SZ, 256, 0, stream>>>(partial, b_skim, W_pol, b_pol, idx);
  gather_pool<<<B_SZ * K_SEL * C_CH * GP_PARTS, 256, 0, stream>>>(F224, idx, pooled_part);
  eval_gemm  <<<B_SZ, 512, 0, stream>>>(pooled_part, W_eval, b_eval, out);
}